// Round 6
// baseline (3191.014 us; speedup 1.0000x reference)
//
#include <hip/hip_runtime.h>
#include <cmath>

// GRU scan, T=128 B=512 D=H=512, split-f16 MFMA (f32-accurate):
//   v = hi + lo/2048 ; a*b ~= ah*bh + (ah*bl + al*bh)/2048
// All GEMM operands live as K-major split-f16 planes in memory -> every MFMA
// fragment is a direct per-lane contiguous f16x8 global load. NO LDS anywhere.
// Phase 0: conv_w (weights -> WT planes), fsplit(h0 -> h ping-pong planes).
// Phase 1 per chunk: fsplit(x) ; gi = x@Wi + bi (big GEMM).
// Phase 2: 128 step kernels (no LDS, no barrier): h@[Wh_r|Wh_z|Wh_n] + gates;
//          epilogue writes h_t as f32 (d_out) AND split-f16 (ping-pong ws).
// d_out = [hT (B*H) | ys (T*B*H)].

#define T_STEPS 128
#define B_SZ 512
#define HD 512

typedef __attribute__((ext_vector_type(8))) _Float16 f16x8;
typedef __attribute__((ext_vector_type(4))) float f32x4;

#define MFMA16(a, b, c) __builtin_amdgcn_mfma_f32_16x16x32_f16((a), (b), (c), 0, 0, 0)

__device__ __forceinline__ float sigf_(float x) { return 1.0f / (1.0f + __expf(-x)); }
__device__ __forceinline__ float tanhf_(float x) { return 1.0f - 2.0f / (__expf(2.0f * x) + 1.0f); }

// ---------------------------------------------------------------------------
// Phase 0: transpose + split weights. WT[n][k]: n<1536 -> Wi col n;
// n>=1536: m=n-1536, g=m>>9, c=m&511: g<2 -> Wh_rz[k][g*512+c]; g==2 -> Wh_n[k][c]
// ---------------------------------------------------------------------------
__global__ __launch_bounds__(256) void conv_w(
    const float* __restrict__ Wi, const float* __restrict__ Wh_rz,
    const float* __restrict__ Wh_n,
    _Float16* __restrict__ WT_hi, _Float16* __restrict__ WT_lo)
{
    __shared__ float Tl[64][65];
    const int tid = threadIdx.x;
    const int k0 = blockIdx.x * 64;
    const int n0 = blockIdx.y * 64;

    const float* base;
    int stride;
    if (n0 < 1536) { base = Wi + n0; stride = 1536; }
    else {
        int m = n0 - 1536, g = m >> 9, c = m & 511;
        if (g < 2) { base = Wh_rz + g * 512 + c; stride = 1024; }
        else       { base = Wh_n + c;            stride = 512; }
    }

    #pragma unroll
    for (int p = 0; p < 4; ++p) {
        int kr = p * 16 + (tid >> 4);
        int nc = (tid & 15) * 4;
        float4 v = *(const float4*)(base + (size_t)(k0 + kr) * stride + nc);
        Tl[kr][nc + 0] = v.x; Tl[kr][nc + 1] = v.y;
        Tl[kr][nc + 2] = v.z; Tl[kr][nc + 3] = v.w;
    }
    __syncthreads();

    const int nr  = tid >> 2;
    const int kc0 = (tid & 3) * 16;
    f16x8 h0v, h1v, l0v, l1v;
    #pragma unroll
    for (int j = 0; j < 16; ++j) {
        float v = Tl[kc0 + j][nr];
        _Float16 th = (_Float16)v;
        _Float16 tl = (_Float16)((v - (float)th) * 2048.0f);
        if (j < 8) { h0v[j] = th; l0v[j] = tl; }
        else       { h1v[j - 8] = th; l1v[j - 8] = tl; }
    }
    size_t o = (size_t)(n0 + nr) * 512 + k0 + kc0;
    *(f16x8*)(WT_hi + o)     = h0v;
    *(f16x8*)(WT_hi + o + 8) = h1v;
    *(f16x8*)(WT_lo + o)     = l0v;
    *(f16x8*)(WT_lo + o + 8) = l1v;
}

// ---------------------------------------------------------------------------
// fsplit: linear f32 -> split f16 planes (layout-preserving). n8 = elems/8.
// ---------------------------------------------------------------------------
__global__ __launch_bounds__(256) void fsplit(
    const float* __restrict__ src,
    _Float16* __restrict__ hi, _Float16* __restrict__ lo, int n8)
{
    const int stride = gridDim.x * 256;
    for (int g = blockIdx.x * 256 + threadIdx.x; g < n8; g += stride) {
        const float* p = src + (size_t)g * 8;
        float4 v0 = *(const float4*)p;
        float4 v1 = *(const float4*)(p + 4);
        float f[8] = {v0.x, v0.y, v0.z, v0.w, v1.x, v1.y, v1.z, v1.w};
        f16x8 hh, ll;
        #pragma unroll
        for (int q = 0; q < 8; ++q) {
            _Float16 th = (_Float16)f[q];
            hh[q] = th;
            ll[q] = (_Float16)((f[q] - (float)th) * 2048.0f);
        }
        *(f16x8*)(hi + (size_t)g * 8) = hh;
        *(f16x8*)(lo + (size_t)g * 8) = ll;
    }
}

// ---------------------------------------------------------------------------
// Phase 1: gi = x @ Wi + bi. LDS-free. Block 128m x 64n, 4 waves (wave = 32m).
// grid (24 n-tiles [fastest], R/128 m-tiles). Full-unroll K, compiler-scheduled.
// ---------------------------------------------------------------------------
__global__ __launch_bounds__(256, 1) void gi_gemm(
    const _Float16* __restrict__ XT_hi, const _Float16* __restrict__ XT_lo, // [R][512]
    const _Float16* __restrict__ WT_hi, const _Float16* __restrict__ WT_lo,
    const float* __restrict__ bi,       // [1536]
    float* __restrict__ gi)             // [R][1536]
{
    const int tid = threadIdx.x;
    const int n0 = blockIdx.x * 64;
    const int m0 = blockIdx.y * 128;
    const int l = tid & 63, w = tid >> 6;
    const int lr = l & 15, lkq = l >> 4, lk = lkq * 8;

    const _Float16* ah_p[2]; const _Float16* al_p[2];
    #pragma unroll
    for (int fm = 0; fm < 2; ++fm) {
        const size_t row = (size_t)(m0 + w * 32 + fm * 16 + lr) * 512 + lk;
        ah_p[fm] = XT_hi + row;
        al_p[fm] = XT_lo + row;
    }
    const _Float16* bh_p[4]; const _Float16* bl_p[4];
    #pragma unroll
    for (int fn = 0; fn < 4; ++fn) {
        const size_t row = (size_t)(n0 + fn * 16 + lr) * 512 + lk;
        bh_p[fn] = WT_hi + row;
        bl_p[fn] = WT_lo + row;
    }

    f32x4 am[2][4], acr[2][4];
    #pragma unroll
    for (int fm = 0; fm < 2; ++fm)
        #pragma unroll
        for (int fn = 0; fn < 4; ++fn) {
            am[fm][fn] = (f32x4){0, 0, 0, 0};
            acr[fm][fn] = (f32x4){0, 0, 0, 0};
        }

    #pragma unroll
    for (int kk = 0; kk < 16; ++kk) {
        const int o = kk * 32;
        f16x8 ah[2], al[2], bh[4], bl[4];
        #pragma unroll
        for (int fm = 0; fm < 2; ++fm) {
            ah[fm] = *(const f16x8*)(ah_p[fm] + o);
            al[fm] = *(const f16x8*)(al_p[fm] + o);
        }
        #pragma unroll
        for (int fn = 0; fn < 4; ++fn) {
            bh[fn] = *(const f16x8*)(bh_p[fn] + o);
            bl[fn] = *(const f16x8*)(bl_p[fn] + o);
        }
        #pragma unroll
        for (int fm = 0; fm < 2; ++fm)
            #pragma unroll
            for (int fn = 0; fn < 4; ++fn) {
                am[fm][fn]  = MFMA16(ah[fm], bh[fn], am[fm][fn]);
                acr[fm][fn] = MFMA16(ah[fm], bl[fn], acr[fm][fn]);
                acr[fm][fn] = MFMA16(al[fm], bh[fn], acr[fm][fn]);
            }
    }

    const float inv = 1.0f / 2048.0f;
    #pragma unroll
    for (int fn = 0; fn < 4; ++fn) {
        const int col = n0 + fn * 16 + lr;
        const float bv = bi[col];
        #pragma unroll
        for (int fm = 0; fm < 2; ++fm)
            #pragma unroll
            for (int i = 0; i < 4; ++i) {
                const int row = m0 + w * 32 + fm * 16 + lkq * 4 + i;
                gi[(size_t)row * 1536 + col] =
                    am[fm][fn][i] + acr[fm][fn][i] * inv + bv;
            }
    }
}

// ---------------------------------------------------------------------------
// Phase 2: step kernel. LDS-free, barrier-free. Tile 32m x 32j x 3 gates,
// grid (16 j, 16 m) = 256 blocks, 4 waves (mh=w>>1, jh=w&1).
// A = split h planes (reset-masked at load), B = weight planes; 2-deep prefetch.
// Epilogue writes h f32 to d_out AND split f16 to ping-pong planes.
// ---------------------------------------------------------------------------
__global__ __launch_bounds__(256, 1) void gru_step(
    const int*   __restrict__ rst,
    const float* __restrict__ hsrc,     // f32 h_{t-1} (for convex combination)
    const _Float16* __restrict__ hs_hi, const _Float16* __restrict__ hs_lo,
    const _Float16* __restrict__ WT_hi, const _Float16* __restrict__ WT_lo,
    const float* __restrict__ gi_t,     // [512][1536] (bi folded in)
    const float* __restrict__ bh_n,     // [512]
    float* __restrict__ hdst,
    float* __restrict__ hT_out,
    _Float16* __restrict__ ho_hi, _Float16* __restrict__ ho_lo)
{
    const int tid = threadIdx.x;
    const int j0 = blockIdx.x * 32;
    const int m0 = blockIdx.y * 32;
    const int l = tid & 63, w = tid >> 6;
    const int mh = w >> 1, jh = w & 1;
    const int lr = l & 15, lkq = l >> 4, lk = lkq * 8;
    const int j = j0 + jh * 16 + lr;
    const int arow = m0 + mh * 16 + lr;
    const bool amask = (rst[arow] != 0);

    // epilogue operands (issued first; consumed last)
    const int rowb = m0 + mh * 16 + lkq * 4;
    float gi_pre[3][4], h_pre[4];
    #pragma unroll
    for (int i = 0; i < 4; ++i) {
        const size_t gb = (size_t)(rowb + i) * 1536 + j;
        gi_pre[0][i] = gi_t[gb];
        gi_pre[1][i] = gi_t[gb + 512];
        gi_pre[2][i] = gi_t[gb + 1024];
        h_pre[i] = hsrc[(size_t)(rowb + i) * 512 + j];
    }

    const _Float16* ah_p = hs_hi + (size_t)arow * 512 + lk;
    const _Float16* al_p = hs_lo + (size_t)arow * 512 + lk;
    const _Float16* bh_p = WT_hi + (size_t)(1536 + j) * 512 + lk;
    const _Float16* bl_p = WT_lo + (size_t)(1536 + j) * 512 + lk;
    constexpr size_t GS = (size_t)512 * 512;
    const f16x8 z8 = {0, 0, 0, 0, 0, 0, 0, 0};

    f32x4 am[3], acr[3];
    #pragma unroll
    for (int g = 0; g < 3; ++g) { am[g] = (f32x4){0,0,0,0}; acr[g] = (f32x4){0,0,0,0}; }

    // 8 streams, 2-deep rolling prefetch
    f16x8 cur[8], nxt[8];
    cur[0] = amask ? z8 : *(const f16x8*)(ah_p);
    cur[1] = amask ? z8 : *(const f16x8*)(al_p);
    cur[2] = *(const f16x8*)(bh_p);
    cur[3] = *(const f16x8*)(bh_p + GS);
    cur[4] = *(const f16x8*)(bh_p + 2 * GS);
    cur[5] = *(const f16x8*)(bl_p);
    cur[6] = *(const f16x8*)(bl_p + GS);
    cur[7] = *(const f16x8*)(bl_p + 2 * GS);
    nxt[0] = amask ? z8 : *(const f16x8*)(ah_p + 32);
    nxt[1] = amask ? z8 : *(const f16x8*)(al_p + 32);
    nxt[2] = *(const f16x8*)(bh_p + 32);
    nxt[3] = *(const f16x8*)(bh_p + GS + 32);
    nxt[4] = *(const f16x8*)(bh_p + 2 * GS + 32);
    nxt[5] = *(const f16x8*)(bl_p + 32);
    nxt[6] = *(const f16x8*)(bl_p + GS + 32);
    nxt[7] = *(const f16x8*)(bl_p + 2 * GS + 32);

    #pragma unroll
    for (int kk = 0; kk < 16; ++kk) {
        f16x8 tmp[8];
        if (kk < 14) {
            const int o = (kk + 2) * 32;
            tmp[0] = amask ? z8 : *(const f16x8*)(ah_p + o);
            tmp[1] = amask ? z8 : *(const f16x8*)(al_p + o);
            tmp[2] = *(const f16x8*)(bh_p + o);
            tmp[3] = *(const f16x8*)(bh_p + GS + o);
            tmp[4] = *(const f16x8*)(bh_p + 2 * GS + o);
            tmp[5] = *(const f16x8*)(bl_p + o);
            tmp[6] = *(const f16x8*)(bl_p + GS + o);
            tmp[7] = *(const f16x8*)(bl_p + 2 * GS + o);
        } else {
            #pragma unroll
            for (int q = 0; q < 8; ++q) tmp[q] = cur[q];
        }
        am[0]  = MFMA16(cur[0], cur[2], am[0]);
        acr[0] = MFMA16(cur[0], cur[5], acr[0]);
        acr[0] = MFMA16(cur[1], cur[2], acr[0]);
        am[1]  = MFMA16(cur[0], cur[3], am[1]);
        acr[1] = MFMA16(cur[0], cur[6], acr[1]);
        acr[1] = MFMA16(cur[1], cur[3], acr[1]);
        am[2]  = MFMA16(cur[0], cur[4], am[2]);
        acr[2] = MFMA16(cur[0], cur[7], acr[2]);
        acr[2] = MFMA16(cur[1], cur[4], acr[2]);
        #pragma unroll
        for (int q = 0; q < 8; ++q) { cur[q] = nxt[q]; nxt[q] = tmp[q]; }
    }

    // ---- epilogue: gates ; write f32 + split f16 ----
    const float bhn = bh_n[j];
    const float inv = 1.0f / 2048.0f;
    #pragma unroll
    for (int i = 0; i < 4; ++i) {
        const int row = rowb + i;
        const bool rm = (rst[row] != 0);
        const float heff = rm ? 0.f : h_pre[i];
        const float r = sigf_(gi_pre[0][i] + am[0][i] + acr[0][i] * inv);
        const float z = sigf_(gi_pre[1][i] + am[1][i] + acr[1][i] * inv);
        const float n = tanhf_(gi_pre[2][i] + r * (am[2][i] + acr[2][i] * inv + bhn));
        const float hv = (1.f - z) * n + z * heff;
        const size_t o = (size_t)row * 512 + j;
        hdst[o] = hv;
        if (hT_out) hT_out[o] = hv;
        const _Float16 th = (_Float16)hv;
        ho_hi[o] = th;
        ho_lo[o] = (_Float16)((hv - (float)th) * 2048.0f);
    }
}

// ---------------------------------------------------------------------------
// Fallback: pure-f32 step kernel (only if d_ws too small).
// ---------------------------------------------------------------------------
constexpr int BM_F = 32, BN_F = 32, BK_F = 32;
constexpr int LDT = BM_F + 4;

__global__ __launch_bounds__(256, 1) void gru_step_f32(
    const float* __restrict__ x, const int* __restrict__ rst,
    const float* __restrict__ h_prev, const float* __restrict__ Wi,
    const float* __restrict__ bi, const float* __restrict__ Wh_rz,
    const float* __restrict__ Wh_n, const float* __restrict__ bh_n,
    float* __restrict__ h_out, float* __restrict__ hT_out)
{
    __shared__ float xs[BK_F][LDT];
    __shared__ float hs[BK_F][LDT];
    __shared__ float wt[6][BK_F][LDT];

    const int tid = threadIdx.x;
    const int bm0 = blockIdx.x * BM_F;
    const int jn0 = blockIdx.y * BN_F;
    const int lrw = tid >> 3;
    const int lcw = (tid & 7) << 2;
    const int ty = tid >> 4, tx = tid & 15;
    const int row0 = 2 * ty, col0 = 2 * tx;

    float aR[2][2] = {{0,0},{0,0}}, aZ[2][2] = {{0,0},{0,0}}, aN[2][2] = {{0,0},{0,0}};
    float hR[2][2] = {{0,0},{0,0}}, hZ[2][2] = {{0,0},{0,0}}, hN[2][2] = {{0,0},{0,0}};

    const int ldrow = bm0 + lrw;
    const bool rmaskld = (rst[ldrow] != 0);
    const float* xrow = x + (size_t)ldrow * 512;
    const float* hrow = h_prev + (size_t)ldrow * 512;

    for (int k0 = 0; k0 < 512; k0 += BK_F) {
        float4 xv = *(const float4*)(xrow + k0 + lcw);
        float4 hv = *(const float4*)(hrow + k0 + lcw);
        if (rmaskld) { hv.x = hv.y = hv.z = hv.w = 0.f; }
        const float* wi_row = Wi + (size_t)(k0 + lrw) * 1536;
        const float* wh_row = Wh_rz + (size_t)(k0 + lrw) * 1024;
        float4 w0v = *(const float4*)(wi_row + jn0 + lcw);
        float4 w1v = *(const float4*)(wi_row + 512 + jn0 + lcw);
        float4 w2v = *(const float4*)(wi_row + 1024 + jn0 + lcw);
        float4 w3v = *(const float4*)(wh_row + jn0 + lcw);
        float4 w4v = *(const float4*)(wh_row + 512 + jn0 + lcw);
        float4 w5v = *(const float4*)(Wh_n + (size_t)(k0 + lrw) * 512 + jn0 + lcw);
        __syncthreads();
        xs[lcw+0][lrw]=xv.x; xs[lcw+1][lrw]=xv.y; xs[lcw+2][lrw]=xv.z; xs[lcw+3][lrw]=xv.w;
        hs[lcw+0][lrw]=hv.x; hs[lcw+1][lrw]=hv.y; hs[lcw+2][lrw]=hv.z; hs[lcw+3][lrw]=hv.w;
        *(float4*)&wt[0][lrw][lcw] = w0v; *(float4*)&wt[1][lrw][lcw] = w1v;
        *(float4*)&wt[2][lrw][lcw] = w2v; *(float4*)&wt[3][lrw][lcw] = w3v;
        *(float4*)&wt[4][lrw][lcw] = w4v; *(float4*)&wt[5][lrw][lcw] = w5v;
        __syncthreads();
        #pragma unroll
        for (int kk = 0; kk < BK_F; ++kk) {
            float2 xa = *(const float2*)&xs[kk][row0];
            float2 ha = *(const float2*)&hs[kk][row0];
            float2 w0 = *(const float2*)&wt[0][kk][col0];
            float2 w1 = *(const float2*)&wt[1][kk][col0];
            float2 w2 = *(const float2*)&wt[2][kk][col0];
            float2 w3 = *(const float2*)&wt[3][kk][col0];
            float2 w4 = *(const float2*)&wt[4][kk][col0];
            float2 w5 = *(const float2*)&wt[5][kk][col0];
            aR[0][0]=fmaf(xa.x,w0.x,aR[0][0]); aR[0][1]=fmaf(xa.x,w0.y,aR[0][1]);
            aR[1][0]=fmaf(xa.y,w0.x,aR[1][0]); aR[1][1]=fmaf(xa.y,w0.y,aR[1][1]);
            aZ[0][0]=fmaf(xa.x,w1.x,aZ[0][0]); aZ[0][1]=fmaf(xa.x,w1.y,aZ[0][1]);
            aZ[1][0]=fmaf(xa.y,w1.x,aZ[1][0]); aZ[1][1]=fmaf(xa.y,w1.y,aZ[1][1]);
            aN[0][0]=fmaf(xa.x,w2.x,aN[0][0]); aN[0][1]=fmaf(xa.x,w2.y,aN[0][1]);
            aN[1][0]=fmaf(xa.y,w2.x,aN[1][0]); aN[1][1]=fmaf(xa.y,w2.y,aN[1][1]);
            hR[0][0]=fmaf(ha.x,w3.x,hR[0][0]); hR[0][1]=fmaf(ha.x,w3.y,hR[0][1]);
            hR[1][0]=fmaf(ha.y,w3.x,hR[1][0]); hR[1][1]=fmaf(ha.y,w3.y,hR[1][1]);
            hZ[0][0]=fmaf(ha.x,w4.x,hZ[0][0]); hZ[0][1]=fmaf(ha.x,w4.y,hZ[0][1]);
            hZ[1][0]=fmaf(ha.y,w4.x,hZ[1][0]); hZ[1][1]=fmaf(ha.y,w4.y,hZ[1][1]);
            hN[0][0]=fmaf(ha.x,w5.x,hN[0][0]); hN[0][1]=fmaf(ha.x,w5.y,hN[0][1]);
            hN[1][0]=fmaf(ha.y,w5.x,hN[1][0]); hN[1][1]=fmaf(ha.y,w5.y,hN[1][1]);
        }
    }
    #pragma unroll
    for (int ii = 0; ii < 2; ++ii) {
        const int b = bm0 + row0 + ii;
        const bool rm = (rst[b] != 0);
        #pragma unroll
        for (int jj = 0; jj < 2; ++jj) {
            const int jn = jn0 + col0 + jj;
            const float heff = rm ? 0.f : h_prev[(size_t)b * 512 + jn];
            const float r = sigf_(aR[ii][jj] + bi[jn] + hR[ii][jj]);
            const float z = sigf_(aZ[ii][jj] + bi[512 + jn] + hZ[ii][jj]);
            const float n = tanhf(aN[ii][jj] + bi[1024 + jn] + r * (hN[ii][jj] + bh_n[jn]));
            const float v = (1.f - z) * n + z * heff;
            h_out[(size_t)b * 512 + jn] = v;
            if (hT_out) hT_out[(size_t)b * 512 + jn] = v;
        }
    }
}

// ---------------------------------------------------------------------------
extern "C" void kernel_launch(void* const* d_in, const int* in_sizes, int n_in,
                              void* d_out, int out_size, void* d_ws, size_t ws_size,
                              hipStream_t stream) {
    const float* h0     = (const float*)d_in[0];
    const float* ins    = (const float*)d_in[1];
    const int*   resets = (const int*)  d_in[2];
    const float* Wi     = (const float*)d_in[3];
    const float* bi     = (const float*)d_in[4];
    const float* Wh_rz  = (const float*)d_in[5];
    const float* Wh_n   = (const float*)d_in[6];
    const float* bh_n   = (const float*)d_in[7];

    float* out = (float*)d_out;
    float* hT  = out;
    float* ys  = out + (size_t)B_SZ * HD;

    const size_t WPLANE = (size_t)3072 * 512;          // weight plane elems
    const size_t HP     = (size_t)512 * 512;           // h plane elems
    const size_t wbytes = WPLANE * 2 * sizeof(_Float16);       // 6.3 MB
    const size_t hbytes = 4 * HP * sizeof(_Float16);           // 2 MB (2 bufs x hi/lo)

    int CH = 0;
    const int cands[8] = {128, 64, 32, 16, 8, 4, 2, 1};
    for (int c = 0; c < 8; ++c) {
        const size_t xt = (size_t)cands[c] * HP * 2 * sizeof(_Float16);
        const size_t gb = (size_t)cands[c] * 512 * 1536 * sizeof(float);
        if (ws_size >= wbytes + hbytes + xt + gb) { CH = cands[c]; break; }
    }

    if (CH > 0) {
        char* p = (char*)d_ws;
        _Float16* WT_hi = (_Float16*)p;            p += WPLANE * 2;
        _Float16* WT_lo = (_Float16*)p;            p += WPLANE * 2;
        _Float16* hsp[2][2];
        hsp[0][0] = (_Float16*)p; p += HP * 2;     // buf0 hi
        hsp[0][1] = (_Float16*)p; p += HP * 2;     // buf0 lo
        hsp[1][0] = (_Float16*)p; p += HP * 2;
        hsp[1][1] = (_Float16*)p; p += HP * 2;
        _Float16* XT_hi = (_Float16*)p;            p += (size_t)CH * HP * 2;
        _Float16* XT_lo = (_Float16*)p;            p += (size_t)CH * HP * 2;
        float* gi = (float*)p;

        conv_w<<<dim3(8, 48), 256, 0, stream>>>(Wi, Wh_rz, Wh_n, WT_hi, WT_lo);
        fsplit<<<128, 256, 0, stream>>>(h0, hsp[0][0], hsp[0][1], (int)(HP / 8));

        for (int t0 = 0; t0 < T_STEPS; t0 += CH) {
            const int n8 = CH * (int)(HP / 8);
            int sgrid = (n8 + 255) / 256; if (sgrid > 4096) sgrid = 4096;
            fsplit<<<sgrid, 256, 0, stream>>>(
                ins + (size_t)t0 * HP, XT_hi, XT_lo, n8);
            gi_gemm<<<dim3(24, CH * 4), 256, 0, stream>>>(
                XT_hi, XT_lo, WT_hi, WT_lo, bi, gi);
            for (int t = t0; t < t0 + CH; ++t) {
                const float* hp = (t == 0) ? h0 : (ys + (size_t)(t - 1) * HP);
                float* ho = ys + (size_t)t * HP;
                const int cb = t & 1, nb = (t + 1) & 1;
                gru_step<<<dim3(16, 16), 256, 0, stream>>>(
                    resets + (size_t)t * 512, hp,
                    hsp[cb][0], hsp[cb][1], WT_hi, WT_lo,
                    gi + (size_t)(t - t0) * 512 * 1536, bh_n,
                    ho, (t == T_STEPS - 1) ? hT : nullptr,
                    hsp[nb][0], hsp[nb][1]);
            }
        }
    } else {
        dim3 grid(B_SZ / BM_F, HD / BN_F);
        for (int t = 0; t < T_STEPS; ++t) {
            const float* hp = (t == 0) ? h0 : (ys + (size_t)(t - 1) * HP);
            float* ho = ys + (size_t)t * HP;
            gru_step_f32<<<grid, 256, 0, stream>>>(
                ins + (size_t)t * HP, resets + (size_t)t * 512,
                hp, Wi, bi, Wh_rz, Wh_n, bh_n,
                ho, (t == T_STEPS - 1) ? hT : nullptr);
        }
    }
}

// Round 7
// 2850.892 us; speedup vs baseline: 1.1193x; 1.1193x over previous
//
#include <hip/hip_runtime.h>
#include <cmath>

// GRU scan, T=128 B=512 D=H=512, split-f16 MFMA (f32-accurate):
//   v = hi + lo/2048 ; a*b ~= ah*bh + (ah*bl + al*bh)/2048
// All GEMM operands pre-split to K-major f16 planes in ws.
// Phase 0: conv_w (weights), fsplit(h0) -> planes.
// Phase 1 per chunk: fsplit(x); gi = x@Wi + bi  (LDS-tiled GEMM, stride-72 pad,
//   reg-staged plane copies -- no in-loop conversion).
// Phase 2: 128 step kernels: h in LDS (plane copy), weights direct-global with
//   3-deep register prefetch; epilogue writes h f32 + split-f16 ping-pong.
// d_out = [hT (B*H) | ys (T*B*H)].

#define T_STEPS 128
#define B_SZ 512
#define HD 512

typedef __attribute__((ext_vector_type(8))) _Float16 f16x8;
typedef __attribute__((ext_vector_type(4))) float f32x4;

#define MFMA16(a, b, c) __builtin_amdgcn_mfma_f32_16x16x32_f16((a), (b), (c), 0, 0, 0)

__device__ __forceinline__ float sigf_(float x) { return 1.0f / (1.0f + __expf(-x)); }
__device__ __forceinline__ float tanhf_(float x) { return 1.0f - 2.0f / (__expf(2.0f * x) + 1.0f); }

// ---------------------------------------------------------------------------
// Phase 0: transpose + split weights. WT[n][k]: n<1536 -> Wi col n;
// n>=1536: m=n-1536, g=m>>9, c=m&511: g<2 -> Wh_rz[k][g*512+c]; g==2 -> Wh_n[k][c]
// ---------------------------------------------------------------------------
__global__ __launch_bounds__(256) void conv_w(
    const float* __restrict__ Wi, const float* __restrict__ Wh_rz,
    const float* __restrict__ Wh_n,
    _Float16* __restrict__ WT_hi, _Float16* __restrict__ WT_lo)
{
    __shared__ float Tl[64][65];
    const int tid = threadIdx.x;
    const int k0 = blockIdx.x * 64;
    const int n0 = blockIdx.y * 64;

    const float* base;
    int stride;
    if (n0 < 1536) { base = Wi + n0; stride = 1536; }
    else {
        int m = n0 - 1536, g = m >> 9, c = m & 511;
        if (g < 2) { base = Wh_rz + g * 512 + c; stride = 1024; }
        else       { base = Wh_n + c;            stride = 512; }
    }

    #pragma unroll
    for (int p = 0; p < 4; ++p) {
        int kr = p * 16 + (tid >> 4);
        int nc = (tid & 15) * 4;
        float4 v = *(const float4*)(base + (size_t)(k0 + kr) * stride + nc);
        Tl[kr][nc + 0] = v.x; Tl[kr][nc + 1] = v.y;
        Tl[kr][nc + 2] = v.z; Tl[kr][nc + 3] = v.w;
    }
    __syncthreads();

    const int nr  = tid >> 2;
    const int kc0 = (tid & 3) * 16;
    f16x8 h0v, h1v, l0v, l1v;
    #pragma unroll
    for (int j = 0; j < 16; ++j) {
        float v = Tl[kc0 + j][nr];
        _Float16 th = (_Float16)v;
        _Float16 tl = (_Float16)((v - (float)th) * 2048.0f);
        if (j < 8) { h0v[j] = th; l0v[j] = tl; }
        else       { h1v[j - 8] = th; l1v[j - 8] = tl; }
    }
    size_t o = (size_t)(n0 + nr) * 512 + k0 + kc0;
    *(f16x8*)(WT_hi + o)     = h0v;
    *(f16x8*)(WT_hi + o + 8) = h1v;
    *(f16x8*)(WT_lo + o)     = l0v;
    *(f16x8*)(WT_lo + o + 8) = l1v;
}

// ---------------------------------------------------------------------------
// fsplit: linear f32 -> split f16 planes. n8 = elems/8.
// ---------------------------------------------------------------------------
__global__ __launch_bounds__(256) void fsplit(
    const float* __restrict__ src,
    _Float16* __restrict__ hi, _Float16* __restrict__ lo, int n8)
{
    const int stride = gridDim.x * 256;
    for (int g = blockIdx.x * 256 + threadIdx.x; g < n8; g += stride) {
        const float* p = src + (size_t)g * 8;
        float4 v0 = *(const float4*)p;
        float4 v1 = *(const float4*)(p + 4);
        float f[8] = {v0.x, v0.y, v0.z, v0.w, v1.x, v1.y, v1.z, v1.w};
        f16x8 hh, ll;
        #pragma unroll
        for (int q = 0; q < 8; ++q) {
            _Float16 th = (_Float16)f[q];
            hh[q] = th;
            ll[q] = (_Float16)((f[q] - (float)th) * 2048.0f);
        }
        *(f16x8*)(hi + (size_t)g * 8) = hh;
        *(f16x8*)(lo + (size_t)g * 8) = ll;
    }
}

// ---------------------------------------------------------------------------
// Phase 1: gi = x @ Wi + bi. Tile 128m x 64n, BK=64, 8 stages, 4 waves.
// LDS [row][72] halfs (2-way banks = free). Reg-staged plane copies; next-stage
// global prefetch issued before compute. grid (24 n-tiles fastest, R/128 m).
// ---------------------------------------------------------------------------
__global__ __launch_bounds__(256, 1) void gi_gemm(
    const _Float16* __restrict__ XT_hi, const _Float16* __restrict__ XT_lo, // [R][512]
    const _Float16* __restrict__ WT_hi, const _Float16* __restrict__ WT_lo,
    const float* __restrict__ bi,       // [1536]
    float* __restrict__ gi)             // [R][1536]
{
    __shared__ __align__(16) _Float16 Ah[128 * 72];
    __shared__ __align__(16) _Float16 Al[128 * 72];
    __shared__ __align__(16) _Float16 Bh[64 * 72];
    __shared__ __align__(16) _Float16 Bl[64 * 72];

    const int tid = threadIdx.x;
    const int n0 = blockIdx.x * 64;
    const int m0 = blockIdx.y * 128;
    const int l = tid & 63, w = tid >> 6;
    const int lr = l & 15, lkq = l >> 4, lk = lkq * 8;

    // staging maps: A chunks c = tid + i*256 (i<4): row=c>>3, off=(c&7)*8
    //               B chunks c = tid + i*256 (i<2)
    const int aRow[4] = { (tid + 0) >> 3, (tid + 256) >> 3, (tid + 512) >> 3, (tid + 768) >> 3 };
    const int aOff = (tid & 7) * 8;

    f16x8 rAh[4], rAl[4], rBh[2], rBl[2];
    // load stage 0
    #pragma unroll
    for (int i = 0; i < 4; ++i) {
        const size_t g = (size_t)(m0 + aRow[i]) * 512 + aOff;
        rAh[i] = *(const f16x8*)(XT_hi + g);
        rAl[i] = *(const f16x8*)(XT_lo + g);
    }
    #pragma unroll
    for (int i = 0; i < 2; ++i) {
        const size_t g = (size_t)(n0 + aRow[i]) * 512 + aOff;   // aRow[i]<64 for i<2
        rBh[i] = *(const f16x8*)(WT_hi + g);
        rBl[i] = *(const f16x8*)(WT_lo + g);
    }

    f32x4 am[2][4], acr[2][4];
    #pragma unroll
    for (int fm = 0; fm < 2; ++fm)
        #pragma unroll
        for (int fn = 0; fn < 4; ++fn) {
            am[fm][fn] = (f32x4){0, 0, 0, 0};
            acr[fm][fn] = (f32x4){0, 0, 0, 0};
        }

    for (int s = 0; s < 8; ++s) {
        __syncthreads();
        #pragma unroll
        for (int i = 0; i < 4; ++i) {
            *(f16x8*)&Ah[aRow[i] * 72 + aOff] = rAh[i];
            *(f16x8*)&Al[aRow[i] * 72 + aOff] = rAl[i];
        }
        #pragma unroll
        for (int i = 0; i < 2; ++i) {
            *(f16x8*)&Bh[aRow[i] * 72 + aOff] = rBh[i];
            *(f16x8*)&Bl[aRow[i] * 72 + aOff] = rBl[i];
        }
        __syncthreads();

        if (s < 7) {
            const int k0 = (s + 1) * 64;
            #pragma unroll
            for (int i = 0; i < 4; ++i) {
                const size_t g = (size_t)(m0 + aRow[i]) * 512 + k0 + aOff;
                rAh[i] = *(const f16x8*)(XT_hi + g);
                rAl[i] = *(const f16x8*)(XT_lo + g);
            }
            #pragma unroll
            for (int i = 0; i < 2; ++i) {
                const size_t g = (size_t)(n0 + aRow[i]) * 512 + k0 + aOff;
                rBh[i] = *(const f16x8*)(WT_hi + g);
                rBl[i] = *(const f16x8*)(WT_lo + g);
            }
        }

        #pragma unroll
        for (int kk = 0; kk < 2; ++kk) {
            const int ko = kk * 32 + lk;
            f16x8 ah[2], al[2], bh[4], bl[4];
            #pragma unroll
            for (int fm = 0; fm < 2; ++fm) {
                ah[fm] = *(const f16x8*)&Ah[(w * 32 + fm * 16 + lr) * 72 + ko];
                al[fm] = *(const f16x8*)&Al[(w * 32 + fm * 16 + lr) * 72 + ko];
            }
            #pragma unroll
            for (int fn = 0; fn < 4; ++fn) {
                bh[fn] = *(const f16x8*)&Bh[(fn * 16 + lr) * 72 + ko];
                bl[fn] = *(const f16x8*)&Bl[(fn * 16 + lr) * 72 + ko];
            }
            #pragma unroll
            for (int fm = 0; fm < 2; ++fm)
                #pragma unroll
                for (int fn = 0; fn < 4; ++fn) {
                    am[fm][fn]  = MFMA16(ah[fm], bh[fn], am[fm][fn]);
                    acr[fm][fn] = MFMA16(ah[fm], bl[fn], acr[fm][fn]);
                    acr[fm][fn] = MFMA16(al[fm], bh[fn], acr[fm][fn]);
                }
        }
    }

    const float inv = 1.0f / 2048.0f;
    #pragma unroll
    for (int fn = 0; fn < 4; ++fn) {
        const int col = n0 + fn * 16 + lr;
        const float bv = bi[col];
        #pragma unroll
        for (int fm = 0; fm < 2; ++fm)
            #pragma unroll
            for (int i = 0; i < 4; ++i) {
                const int row = m0 + w * 32 + fm * 16 + lkq * 4 + i;
                gi[(size_t)row * 1536 + col] =
                    am[fm][fn][i] + acr[fm][fn][i] * inv + bv;
            }
    }
}

// ---------------------------------------------------------------------------
// Phase 2: step kernel. Tile 32m x 32j x 3 gates, grid (16j, 16m), 4 waves.
// h planes copied to LDS [32][520] (no conversion); weights direct-global,
// 3-deep prefetch; ONE barrier; epilogue writes f32 + split planes.
// ---------------------------------------------------------------------------
__global__ __launch_bounds__(256, 1) void gru_step(
    const int*   __restrict__ rst,
    const float* __restrict__ hsrc,     // f32 h_{t-1}
    const _Float16* __restrict__ hs_hi, const _Float16* __restrict__ hs_lo,
    const _Float16* __restrict__ WT_hi, const _Float16* __restrict__ WT_lo,
    const float* __restrict__ gi_t,     // [512][1536]
    const float* __restrict__ bh_n,
    float* __restrict__ hdst,
    float* __restrict__ hT_out,
    _Float16* __restrict__ ho_hi, _Float16* __restrict__ ho_lo)
{
    __shared__ __align__(16) _Float16 Ah[32 * 520];
    __shared__ __align__(16) _Float16 Al[32 * 520];

    const int tid = threadIdx.x;
    const int j0 = blockIdx.x * 32;
    const int m0 = blockIdx.y * 32;
    const int l = tid & 63, w = tid >> 6;
    const int mh = w >> 1, jh = w & 1;
    const int lr = l & 15, lkq = l >> 4, lk = lkq * 8;
    const int j = j0 + jh * 16 + lr;

    // epilogue operands (issued early)
    const int rowb = m0 + mh * 16 + lkq * 4;
    float gi_pre[3][4], h_pre[4];
    #pragma unroll
    for (int i = 0; i < 4; ++i) {
        const size_t gb = (size_t)(rowb + i) * 1536 + j;
        gi_pre[0][i] = gi_t[gb];
        gi_pre[1][i] = gi_t[gb + 512];
        gi_pre[2][i] = gi_t[gb + 1024];
        h_pre[i] = hsrc[(size_t)(rowb + i) * 512 + j];
    }

    // weight streams: 3-deep prefetch
    const _Float16* bh_p = WT_hi + (size_t)(1536 + j) * 512 + lk;
    const _Float16* bl_p = WT_lo + (size_t)(1536 + j) * 512 + lk;
    constexpr size_t GS = (size_t)512 * 512;

    f16x8 buf[3][6];
    #pragma unroll
    for (int d = 0; d < 3; ++d) {
        const int o = d * 32;
        buf[d][0] = *(const f16x8*)(bh_p + o);
        buf[d][1] = *(const f16x8*)(bh_p + GS + o);
        buf[d][2] = *(const f16x8*)(bh_p + 2 * GS + o);
        buf[d][3] = *(const f16x8*)(bl_p + o);
        buf[d][4] = *(const f16x8*)(bl_p + GS + o);
        buf[d][5] = *(const f16x8*)(bl_p + 2 * GS + o);
    }

    // stage h planes (pure copy + reset mask): 8 chunks per thread per plane
    {
        const int srow = tid >> 3;
        const int sc0  = (tid & 7) * 8;
        const bool smask = (rst[m0 + srow] != 0);
        const f16x8 z8 = {0, 0, 0, 0, 0, 0, 0, 0};
        const _Float16* ph = hs_hi + (size_t)(m0 + srow) * 512;
        const _Float16* pl = hs_lo + (size_t)(m0 + srow) * 512;
        #pragma unroll
        for (int c = 0; c < 8; ++c) {
            const int col = c * 64 + sc0;
            *(f16x8*)&Ah[srow * 520 + col] = smask ? z8 : *(const f16x8*)(ph + col);
            *(f16x8*)&Al[srow * 520 + col] = smask ? z8 : *(const f16x8*)(pl + col);
        }
    }
    __syncthreads();

    f32x4 am[3], acr[3];
    #pragma unroll
    for (int g = 0; g < 3; ++g) { am[g] = (f32x4){0,0,0,0}; acr[g] = (f32x4){0,0,0,0}; }

    const int abase = (mh * 16 + lr) * 520 + lk;
    #pragma unroll
    for (int kk = 0; kk < 16; ++kk) {
        const int s = kk % 3;
        f16x8 ah = *(const f16x8*)&Ah[abase + kk * 32];
        f16x8 al = *(const f16x8*)&Al[abase + kk * 32];
        am[0]  = MFMA16(ah, buf[s][0], am[0]);
        acr[0] = MFMA16(ah, buf[s][3], acr[0]);
        acr[0] = MFMA16(al, buf[s][0], acr[0]);
        am[1]  = MFMA16(ah, buf[s][1], am[1]);
        acr[1] = MFMA16(ah, buf[s][4], acr[1]);
        acr[1] = MFMA16(al, buf[s][1], acr[1]);
        am[2]  = MFMA16(ah, buf[s][2], am[2]);
        acr[2] = MFMA16(ah, buf[s][5], acr[2]);
        acr[2] = MFMA16(al, buf[s][2], acr[2]);
        if (kk < 13) {
            const int o = (kk + 3) * 32;
            buf[s][0] = *(const f16x8*)(bh_p + o);
            buf[s][1] = *(const f16x8*)(bh_p + GS + o);
            buf[s][2] = *(const f16x8*)(bh_p + 2 * GS + o);
            buf[s][3] = *(const f16x8*)(bl_p + o);
            buf[s][4] = *(const f16x8*)(bl_p + GS + o);
            buf[s][5] = *(const f16x8*)(bl_p + 2 * GS + o);
        }
    }

    // epilogue
    const float bhn = bh_n[j];
    const float inv = 1.0f / 2048.0f;
    #pragma unroll
    for (int i = 0; i < 4; ++i) {
        const int row = rowb + i;
        const bool rm = (rst[row] != 0);
        const float heff = rm ? 0.f : h_pre[i];
        const float r = sigf_(gi_pre[0][i] + am[0][i] + acr[0][i] * inv);
        const float z = sigf_(gi_pre[1][i] + am[1][i] + acr[1][i] * inv);
        const float n = tanhf_(gi_pre[2][i] + r * (am[2][i] + acr[2][i] * inv + bhn));
        const float hv = (1.f - z) * n + z * heff;
        const size_t o = (size_t)row * 512 + j;
        hdst[o] = hv;
        if (hT_out) hT_out[o] = hv;
        const _Float16 th = (_Float16)hv;
        ho_hi[o] = th;
        ho_lo[o] = (_Float16)((hv - (float)th) * 2048.0f);
    }
}

// ---------------------------------------------------------------------------
// Fallback: pure-f32 step kernel (only if d_ws too small).
// ---------------------------------------------------------------------------
constexpr int BM_F = 32, BN_F = 32, BK_F = 32;
constexpr int LDT = BM_F + 4;

__global__ __launch_bounds__(256, 1) void gru_step_f32(
    const float* __restrict__ x, const int* __restrict__ rst,
    const float* __restrict__ h_prev, const float* __restrict__ Wi,
    const float* __restrict__ bi, const float* __restrict__ Wh_rz,
    const float* __restrict__ Wh_n, const float* __restrict__ bh_n,
    float* __restrict__ h_out, float* __restrict__ hT_out)
{
    __shared__ float xs[BK_F][LDT];
    __shared__ float hs[BK_F][LDT];
    __shared__ float wt[6][BK_F][LDT];

    const int tid = threadIdx.x;
    const int bm0 = blockIdx.x * BM_F;
    const int jn0 = blockIdx.y * BN_F;
    const int lrw = tid >> 3;
    const int lcw = (tid & 7) << 2;
    const int ty = tid >> 4, tx = tid & 15;
    const int row0 = 2 * ty, col0 = 2 * tx;

    float aR[2][2] = {{0,0},{0,0}}, aZ[2][2] = {{0,0},{0,0}}, aN[2][2] = {{0,0},{0,0}};
    float hR[2][2] = {{0,0},{0,0}}, hZ[2][2] = {{0,0},{0,0}}, hN[2][2] = {{0,0},{0,0}};

    const int ldrow = bm0 + lrw;
    const bool rmaskld = (rst[ldrow] != 0);
    const float* xrow = x + (size_t)ldrow * 512;
    const float* hrow = h_prev + (size_t)ldrow * 512;

    for (int k0 = 0; k0 < 512; k0 += BK_F) {
        float4 xv = *(const float4*)(xrow + k0 + lcw);
        float4 hv = *(const float4*)(hrow + k0 + lcw);
        if (rmaskld) { hv.x = hv.y = hv.z = hv.w = 0.f; }
        const float* wi_row = Wi + (size_t)(k0 + lrw) * 1536;
        const float* wh_row = Wh_rz + (size_t)(k0 + lrw) * 1024;
        float4 w0v = *(const float4*)(wi_row + jn0 + lcw);
        float4 w1v = *(const float4*)(wi_row + 512 + jn0 + lcw);
        float4 w2v = *(const float4*)(wi_row + 1024 + jn0 + lcw);
        float4 w3v = *(const float4*)(wh_row + jn0 + lcw);
        float4 w4v = *(const float4*)(wh_row + 512 + jn0 + lcw);
        float4 w5v = *(const float4*)(Wh_n + (size_t)(k0 + lrw) * 512 + jn0 + lcw);
        __syncthreads();
        xs[lcw+0][lrw]=xv.x; xs[lcw+1][lrw]=xv.y; xs[lcw+2][lrw]=xv.z; xs[lcw+3][lrw]=xv.w;
        hs[lcw+0][lrw]=hv.x; hs[lcw+1][lrw]=hv.y; hs[lcw+2][lrw]=hv.z; hs[lcw+3][lrw]=hv.w;
        *(float4*)&wt[0][lrw][lcw] = w0v; *(float4*)&wt[1][lrw][lcw] = w1v;
        *(float4*)&wt[2][lrw][lcw] = w2v; *(float4*)&wt[3][lrw][lcw] = w3v;
        *(float4*)&wt[4][lrw][lcw] = w4v; *(float4*)&wt[5][lrw][lcw] = w5v;
        __syncthreads();
        #pragma unroll
        for (int kk = 0; kk < BK_F; ++kk) {
            float2 xa = *(const float2*)&xs[kk][row0];
            float2 ha = *(const float2*)&hs[kk][row0];
            float2 w0 = *(const float2*)&wt[0][kk][col0];
            float2 w1 = *(const float2*)&wt[1][kk][col0];
            float2 w2 = *(const float2*)&wt[2][kk][col0];
            float2 w3 = *(const float2*)&wt[3][kk][col0];
            float2 w4 = *(const float2*)&wt[4][kk][col0];
            float2 w5 = *(const float2*)&wt[5][kk][col0];
            aR[0][0]=fmaf(xa.x,w0.x,aR[0][0]); aR[0][1]=fmaf(xa.x,w0.y,aR[0][1]);
            aR[1][0]=fmaf(xa.y,w0.x,aR[1][0]); aR[1][1]=fmaf(xa.y,w0.y,aR[1][1]);
            aZ[0][0]=fmaf(xa.x,w1.x,aZ[0][0]); aZ[0][1]=fmaf(xa.x,w1.y,aZ[0][1]);
            aZ[1][0]=fmaf(xa.y,w1.x,aZ[1][0]); aZ[1][1]=fmaf(xa.y,w1.y,aZ[1][1]);
            aN[0][0]=fmaf(xa.x,w2.x,aN[0][0]); aN[0][1]=fmaf(xa.x,w2.y,aN[0][1]);
            aN[1][0]=fmaf(xa.y,w2.x,aN[1][0]); aN[1][1]=fmaf(xa.y,w2.y,aN[1][1]);
            hR[0][0]=fmaf(ha.x,w3.x,hR[0][0]); hR[0][1]=fmaf(ha.x,w3.y,hR[0][1]);
            hR[1][0]=fmaf(ha.y,w3.x,hR[1][0]); hR[1][1]=fmaf(ha.y,w3.y,hR[1][1]);
            hZ[0][0]=fmaf(ha.x,w4.x,hZ[0][0]); hZ[0][1]=fmaf(ha.x,w4.y,hZ[0][1]);
            hZ[1][0]=fmaf(ha.y,w4.x,hZ[1][0]); hZ[1][1]=fmaf(ha.y,w4.y,hZ[1][1]);
            hN[0][0]=fmaf(ha.x,w5.x,hN[0][0]); hN[0][1]=fmaf(ha.x,w5.y,hN[0][1]);
            hN[1][0]=fmaf(ha.y,w5.x,hN[1][0]); hN[1][1]=fmaf(ha.y,w5.y,hN[1][1]);
        }
    }
    #pragma unroll
    for (int ii = 0; ii < 2; ++ii) {
        const int b = bm0 + row0 + ii;
        const bool rm = (rst[b] != 0);
        #pragma unroll
        for (int jj = 0; jj < 2; ++jj) {
            const int jn = jn0 + col0 + jj;
            const float heff = rm ? 0.f : h_prev[(size_t)b * 512 + jn];
            const float r = sigf_(aR[ii][jj] + bi[jn] + hR[ii][jj]);
            const float z = sigf_(aZ[ii][jj] + bi[512 + jn] + hZ[ii][jj]);
            const float n = tanhf(aN[ii][jj] + bi[1024 + jn] + r * (hN[ii][jj] + bh_n[jn]));
            const float v = (1.f - z) * n + z * heff;
            h_out[(size_t)b * 512 + jn] = v;
            if (hT_out) hT_out[(size_t)b * 512 + jn] = v;
        }
    }
}

// ---------------------------------------------------------------------------
extern "C" void kernel_launch(void* const* d_in, const int* in_sizes, int n_in,
                              void* d_out, int out_size, void* d_ws, size_t ws_size,
                              hipStream_t stream) {
    const float* h0     = (const float*)d_in[0];
    const float* ins    = (const float*)d_in[1];
    const int*   resets = (const int*)  d_in[2];
    const float* Wi     = (const float*)d_in[3];
    const float* bi     = (const float*)d_in[4];
    const float* Wh_rz  = (const float*)d_in[5];
    const float* Wh_n   = (const float*)d_in[6];
    const float* bh_n   = (const float*)d_in[7];

    float* out = (float*)d_out;
    float* hT  = out;
    float* ys  = out + (size_t)B_SZ * HD;

    const size_t WPLANE = (size_t)3072 * 512;
    const size_t HP     = (size_t)512 * 512;
    const size_t wbytes = WPLANE * 2 * sizeof(_Float16);   // 6.3 MB
    const size_t hbytes = 4 * HP * sizeof(_Float16);       // 2 MB ping-pong

    int CH = 0;
    const int cands[8] = {128, 64, 32, 16, 8, 4, 2, 1};
    for (int c = 0; c < 8; ++c) {
        const size_t xt = (size_t)cands[c] * HP * 2 * sizeof(_Float16);
        const size_t gb = (size_t)cands[c] * 512 * 1536 * sizeof(float);
        if (ws_size >= wbytes + hbytes + xt + gb) { CH = cands[c]; break; }
    }

    if (CH > 0) {
        char* p = (char*)d_ws;
        _Float16* WT_hi = (_Float16*)p;            p += WPLANE * 2;
        _Float16* WT_lo = (_Float16*)p;            p += WPLANE * 2;
        _Float16* hsp[2][2];
        hsp[0][0] = (_Float16*)p; p += HP * 2;
        hsp[0][1] = (_Float16*)p; p += HP * 2;
        hsp[1][0] = (_Float16*)p; p += HP * 2;
        hsp[1][1] = (_Float16*)p; p += HP * 2;
        _Float16* XT_hi = (_Float16*)p;            p += (size_t)CH * HP * 2;
        _Float16* XT_lo = (_Float16*)p;            p += (size_t)CH * HP * 2;
        float* gi = (float*)p;

        conv_w<<<dim3(8, 48), 256, 0, stream>>>(Wi, Wh_rz, Wh_n, WT_hi, WT_lo);
        fsplit<<<128, 256, 0, stream>>>(h0, hsp[0][0], hsp[0][1], (int)(HP / 8));

        for (int t0 = 0; t0 < T_STEPS; t0 += CH) {
            const int n8 = CH * (int)(HP / 8);
            int sgrid = (n8 + 255) / 256; if (sgrid > 4096) sgrid = 4096;
            fsplit<<<sgrid, 256, 0, stream>>>(
                ins + (size_t)t0 * HP, XT_hi, XT_lo, n8);
            gi_gemm<<<dim3(24, CH * 4), 256, 0, stream>>>(
                XT_hi, XT_lo, WT_hi, WT_lo, bi, gi);
            for (int t = t0; t < t0 + CH; ++t) {
                const float* hp = (t == 0) ? h0 : (ys + (size_t)(t - 1) * HP);
                float* ho = ys + (size_t)t * HP;
                const int cb = t & 1, nb = (t + 1) & 1;
                gru_step<<<dim3(16, 16), 256, 0, stream>>>(
                    resets + (size_t)t * 512, hp,
                    hsp[cb][0], hsp[cb][1], WT_hi, WT_lo,
                    gi + (size_t)(t - t0) * 512 * 1536, bh_n,
                    ho, (t == T_STEPS - 1) ? hT : nullptr,
                    hsp[nb][0], hsp[nb][1]);
            }
        }
    } else {
        dim3 grid(B_SZ / BM_F, HD / BN_F);
        for (int t = 0; t < T_STEPS; ++t) {
            const float* hp = (t == 0) ? h0 : (ys + (size_t)(t - 1) * HP);
            float* ho = ys + (size_t)t * HP;
            gru_step_f32<<<grid, 256, 0, stream>>>(
                ins + (size_t)t * HP, resets + (size_t)t * 512,
                hp, Wi, bi, Wh_rz, Wh_n, bh_n,
                ho, (t == T_STEPS - 1) ? hT : nullptr);
        }
    }
}